// Round 9
// baseline (311.631 us; speedup 1.0000x reference)
//
#include <hip/hip_runtime.h>
#include <math.h>

#define SEQ     2048
#define HID     2048
#define NH      32
#define NKV     8
#define HD      64
#define QCOLS   (NH*HD)          // 2048
#define KVCOLS  (NKV*HD)         // 512
#define NCK     4                // kv split chunks

#define LDP2 66   // P LDS row stride (bf16 el)

typedef __attribute__((ext_vector_type(8))) short bf8_t;   // 8 bf16 (4 VGPRs)
typedef __attribute__((ext_vector_type(4))) float f4_t;    // C/D frag

typedef __attribute__((address_space(1))) const unsigned int glb_u32;
typedef __attribute__((address_space(3))) unsigned int lds_u32;

__device__ inline unsigned short f2bf(float f) {
    union { float f; unsigned int u; } a; a.f = f;
    unsigned int u = a.u;
    u += 0x7fffu + ((u >> 16) & 1u);
    return (unsigned short)(u >> 16);
}
__device__ inline float bf2f(unsigned short b) {
    union { unsigned int u; float f; } a; a.u = ((unsigned int)b) << 16;
    return a.f;
}

// ---------------------------------------------------------------------------
__global__ void rope_table_kernel(float* __restrict__ cosT, float* __restrict__ sinT) {
    int i = blockIdx.x * blockDim.x + threadIdx.x;
    int srow = i >> 6;
    int d = i & 63;
    float inv = powf(500000.0f, -(float)(d & 31) / 32.0f);
    float a = (float)srow * inv;
    cosT[i] = cosf(a);
    sinT[i] = sinf(a);
}

// ---------------------------------------------------------------------------
__global__ void convert_x_kernel(const float* __restrict__ X, unsigned short* __restrict__ Xb) {
    int i = blockIdx.x * blockDim.x + threadIdx.x;
    float4 v = *(const float4*)&X[(size_t)i * 4];
    ushort4 o;
    o.x = f2bf(v.x); o.y = f2bf(v.y); o.z = f2bf(v.z); o.w = f2bf(v.w);
    *(ushort4*)&Xb[(size_t)i * 4] = o;
}

// ---------------------------------------------------------------------------
__global__ __launch_bounds__(256) void transpose_all_kernel(
    const float* __restrict__ Wq, const float* __restrict__ Wk,
    const float* __restrict__ Wv, const float* __restrict__ Wo,
    unsigned short* __restrict__ WT, unsigned short* __restrict__ WoT)
{
    __shared__ float tile[32][33];
    int R0 = blockIdx.x * 32;
    int k0 = blockIdx.y * 32;
    const float* W; int N; int n0; unsigned short* dst; int drow;
    if (R0 < 2048)      { W = Wq; N = 2048; n0 = R0;        dst = WT;  drow = R0; }
    else if (R0 < 2560) { W = Wk; N = 512;  n0 = R0 - 2048; dst = WT;  drow = R0; }
    else if (R0 < 3072) { W = Wv; N = 512;  n0 = R0 - 2560; dst = WT;  drow = R0; }
    else                { W = Wo; N = 2048; n0 = R0 - 3072; dst = WoT; drow = R0 - 3072; }

    int t = threadIdx.x;
    int tx = t & 31, ty = t >> 5;
    #pragma unroll
    for (int i = 0; i < 4; ++i) {
        int k = ty + i * 8;
        tile[k][tx] = W[(size_t)(k0 + k) * N + n0 + tx];
    }
    __syncthreads();
    #pragma unroll
    for (int i = 0; i < 4; ++i) {
        int n = ty + i * 8;
        dst[(size_t)(drow + n) * HID + k0 + tx] = f2bf(tile[tx][n]);
    }
}

// ===========================================================================
// GEMM core: 128x128 tile, BK=64, double-buffered global_load_lds staging.
// Issue-early / wait-late: stage(next) before compute(cur), 1 barrier/iter.
// ===========================================================================
__device__ __forceinline__ void gemm_core128(
    const unsigned short* __restrict__ A, const unsigned short* __restrict__ BT,
    unsigned short* As, unsigned short* Bs,   // each 2 x 128*64
    int m0, int n0, int t, f4_t acc[4][4])
{
    int lane = t & 63, wid = t >> 6;
    int l16 = lane & 15, g4 = lane >> 4;
    int wr = wid >> 1, wc = wid & 1;

    const unsigned short* Ap = A  + (size_t)(m0 + (t >> 3)) * HID + (t & 7) * 8;
    const unsigned short* Bp = BT + (size_t)(n0 + (t >> 3)) * HID + (t & 7) * 8;
    unsigned short* AsW = As + wid * 512;
    unsigned short* BsW = Bs + wid * 512;

#define STAGE_GEMM(buf, kk)                                                               \
    {                                                                                     \
        _Pragma("unroll")                                                                 \
        for (int c = 0; c < 4; ++c)                                                       \
            __builtin_amdgcn_global_load_lds((glb_u32*)(Ap + (size_t)(32 * c) * HID + (kk)), \
                                             (lds_u32*)(AsW + (buf) * 8192 + c * 2048), 16, 0, 0); \
        _Pragma("unroll")                                                                 \
        for (int c = 0; c < 4; ++c)                                                       \
            __builtin_amdgcn_global_load_lds((glb_u32*)(Bp + (size_t)(32 * c) * HID + (kk)), \
                                             (lds_u32*)(BsW + (buf) * 8192 + c * 2048), 16, 0, 0); \
    }

    STAGE_GEMM(0, 0)
    __syncthreads();
    int cur = 0;
    for (int k0 = 0; k0 < HID; k0 += 64) {
        if (k0 + 64 < HID) { STAGE_GEMM(cur ^ 1, k0 + 64) }
        const unsigned short* Ab = As + cur * 8192;
        const unsigned short* Bb = Bs + cur * 8192;
        #pragma unroll
        for (int kc = 0; kc < 2; ++kc) {
            bf8_t af[4], bfr[4];
            #pragma unroll
            for (int mi = 0; mi < 4; ++mi)
                af[mi] = *(const bf8_t*)&Ab[(wr * 64 + mi * 16 + l16) * 64 + 32 * kc + 8 * g4];
            #pragma unroll
            for (int ni = 0; ni < 4; ++ni)
                bfr[ni] = *(const bf8_t*)&Bb[(wc * 64 + ni * 16 + l16) * 64 + 32 * kc + 8 * g4];
            #pragma unroll
            for (int mi = 0; mi < 4; ++mi)
                #pragma unroll
                for (int ni = 0; ni < 4; ++ni)
                    acc[mi][ni] = __builtin_amdgcn_mfma_f32_16x16x32_bf16(af[mi], bfr[ni], acc[mi][ni], 0, 0, 0);
        }
        __syncthreads();   // drains prefetch (hid under compute) + LDS reads
        cur ^= 1;
    }
#undef STAGE_GEMM
}

// K1: QKV projection with RoPE epilogue; Q gets softmax scale folded in.
__global__ __launch_bounds__(256) void qkv_mfma_kernel(
    const unsigned short* __restrict__ A, const unsigned short* __restrict__ BT,
    const float* __restrict__ cosT, const float* __restrict__ sinT,
    unsigned short* __restrict__ Q, unsigned short* __restrict__ Ko,
    unsigned short* __restrict__ Vo)
{
    __shared__ unsigned short As[2 * 128 * 64];
    __shared__ unsigned short Bs[2 * 128 * 64];
    int n0 = blockIdx.x * 128, m0 = blockIdx.y * 128;
    int t = threadIdx.x;
    int lane = t & 63, wid = t >> 6;
    int l16 = lane & 15, g4 = lane >> 4;
    int wr = wid >> 1, wc = wid & 1;

    f4_t acc[4][4];
    #pragma unroll
    for (int mi = 0; mi < 4; ++mi)
        #pragma unroll
        for (int ni = 0; ni < 4; ++ni) acc[mi][ni] = (f4_t){0.f, 0.f, 0.f, 0.f};

    gemm_core128(A, BT, As, Bs, m0, n0, t, acc);

    #pragma unroll
    for (int ni = 0; ni < 4; ++ni) {
        int n = n0 + wc * 64 + ni * 16 + l16;
        int d = n & 63;
        int odd = n & 1;
        #pragma unroll
        for (int mi = 0; mi < 4; ++mi) {
            #pragma unroll
            for (int r = 0; r < 4; ++r) {
                float x = acc[mi][ni][r];
                float xp = __shfl_xor(x, 1);
                int s = m0 + wr * 64 + mi * 16 + g4 * 4 + r;
                float val;
                if (n < QCOLS + KVCOLS) {
                    float cv = cosT[s * HD + d], sv = sinT[s * HD + d];
                    val = odd ? x * cv + xp * sv : x * cv - xp * sv;
                } else val = x;
                if (n < QCOLS) val *= 0.125f;
                unsigned short ob = f2bf(val);
                if (n < QCOLS)                   Q[(size_t)s * QCOLS + n] = ob;
                else if (n < QCOLS + KVCOLS)     Ko[(size_t)s * KVCOLS + n - QCOLS] = ob;
                else                             Vo[(size_t)s * KVCOLS + n - QCOLS - KVCOLS] = ob;
            }
        }
    }
}

// K3: output projection (fp32 out)
__global__ __launch_bounds__(256) void out_mfma_kernel(
    const unsigned short* __restrict__ A, const unsigned short* __restrict__ BT,
    float* __restrict__ C)
{
    __shared__ unsigned short As[2 * 128 * 64];
    __shared__ unsigned short Bs[2 * 128 * 64];
    int n0 = blockIdx.x * 128, m0 = blockIdx.y * 128;
    int t = threadIdx.x;
    int lane = t & 63, wid = t >> 6;
    int l16 = lane & 15, g4 = lane >> 4;
    int wr = wid >> 1, wc = wid & 1;

    f4_t acc[4][4];
    #pragma unroll
    for (int mi = 0; mi < 4; ++mi)
        #pragma unroll
        for (int ni = 0; ni < 4; ++ni) acc[mi][ni] = (f4_t){0.f, 0.f, 0.f, 0.f};

    gemm_core128(A, BT, As, Bs, m0, n0, t, acc);

    #pragma unroll
    for (int ni = 0; ni < 4; ++ni) {
        int n = n0 + wc * 64 + ni * 16 + l16;
        #pragma unroll
        for (int mi = 0; mi < 4; ++mi) {
            #pragma unroll
            for (int r = 0; r < 4; ++r) {
                int s = m0 + wr * 64 + mi * 16 + g4 * 4 + r;
                C[(size_t)s * HID + n] = acc[mi][ni][r];
            }
        }
    }
}

// ---------------------------------------------------------------------------
// K1b: V -> V^T global ([s][kvh*64+d] -> [kvh][d][s])
// ---------------------------------------------------------------------------
__global__ __launch_bounds__(256) void transpose_v_kernel(
    const unsigned short* __restrict__ Vb, unsigned short* __restrict__ Vtg)
{
    __shared__ unsigned short tile[64][72];
    int s0 = blockIdx.x * 64;
    int kvh = blockIdx.y;
    int t = threadIdx.x;
    int r = t >> 3, c = t & 7;
    #pragma unroll
    for (int i = 0; i < 2; ++i) {
        int row = r + i * 32;
        *(bf8_t*)&tile[row][c * 8] =
            *(const bf8_t*)&Vb[(size_t)(s0 + row) * KVCOLS + kvh * HD + c * 8];
    }
    __syncthreads();
    int d = t >> 2, sc = (t & 3) * 16;
    unsigned short ob[16];
    #pragma unroll
    for (int j = 0; j < 16; ++j) ob[j] = tile[sc + j][d];
    *(bf8_t*)&Vtg[(size_t)(kvh * HD + d) * SEQ + s0 + sc]     = *(bf8_t*)&ob[0];
    *(bf8_t*)&Vtg[(size_t)(kvh * HD + d) * SEQ + s0 + sc + 8] = *(bf8_t*)&ob[8];
}

// ===========================================================================
// K2: causal flash attention — barrier-free, swapped QK^T, global K/V frags.
// Block (pr, h, ck): kv-tiles kt ≡ ck (mod 4). Defer-max THR=8.
// ===========================================================================
__global__ __launch_bounds__(256, 2) void attn_mfma_kernel(
    const unsigned short* __restrict__ Q, const unsigned short* __restrict__ K,
    const unsigned short* __restrict__ Vt,
    unsigned short* __restrict__ Opart, float* __restrict__ mlpart)
{
    __shared__ unsigned short Ps[4][32 * LDP2];
    int pr = blockIdx.x;            // 0..7
    int h  = blockIdx.y;
    int ck = blockIdx.z;            // kv chunk 0..3
    int kvh = h >> 2;
    int t = threadIdx.x;
    int w = t >> 6, lane = t & 63, l16 = lane & 15, g4 = lane >> 4;

    int qb[2];    qb[0] = pr * 128 + w * 32;  qb[1] = (15 - pr) * 128 + w * 32;
    int ktmax[2]; ktmax[0] = 2 * pr + 1;      ktmax[1] = 2 * (15 - pr) + 1;

    const unsigned short* Kb_ = K + kvh * HD;
    const unsigned short* Vb_ = Vt + (size_t)kvh * HD * SEQ;
    unsigned short* PsW = &Ps[w][0];

    bf8_t qa[2][2][2];
    #pragma unroll
    for (int b = 0; b < 2; ++b)
        #pragma unroll
        for (int ns = 0; ns < 2; ++ns)
            #pragma unroll
            for (int kc = 0; kc < 2; ++kc)
                qa[b][ns][kc] = *(const bf8_t*)&Q[(size_t)(qb[b] + ns * 16 + l16) * QCOLS
                                                  + h * HD + kc * 32 + 8 * g4];

    f4_t o[2][2][4];
    float ms[2][2], ls[2][2];
    #pragma unroll
    for (int b = 0; b < 2; ++b)
        #pragma unroll
        for (int ns = 0; ns < 2; ++ns) {
            ms[b][ns] = -1e30f; ls[b][ns] = 0.f;
            #pragma unroll
            for (int mt = 0; mt < 4; ++mt) o[b][ns][mt] = (f4_t){0.f, 0.f, 0.f, 0.f};
        }

    for (int kt = ck; kt <= ktmax[1]; kt += NCK) {
        int kv0 = kt * 64;
        #pragma unroll
        for (int b = 1; b >= 0; --b) {
            if (b == 0 && kt > ktmax[0]) continue;
            if (kv0 > qb[b] + 31) continue;           // wave fully masked

            // ---- S^T = K · Q ----
            f4_t s[2][4];
            #pragma unroll
            for (int ns = 0; ns < 2; ++ns)
                #pragma unroll
                for (int mt = 0; mt < 4; ++mt) s[ns][mt] = (f4_t){0.f, 0.f, 0.f, 0.f};
            #pragma unroll
            for (int kc = 0; kc < 2; ++kc) {
                bf8_t af[4];
                #pragma unroll
                for (int mt = 0; mt < 4; ++mt)
                    af[mt] = *(const bf8_t*)&Kb_[(size_t)(kv0 + mt * 16 + l16) * KVCOLS
                                                 + kc * 32 + 8 * g4];
                #pragma unroll
                for (int mt = 0; mt < 4; ++mt)
                    #pragma unroll
                    for (int ns = 0; ns < 2; ++ns)
                        s[ns][mt] = __builtin_amdgcn_mfma_f32_16x16x32_bf16(
                            af[mt], qa[b][ns][kc], s[ns][mt], 0, 0, 0);
            }

            // ---- in-lane online softmax (q = l16), defer-max THR=8 ----
            #pragma unroll
            for (int ns = 0; ns < 2; ++ns) {
                int qg = qb[b] + ns * 16 + l16;
                float x[16];
                float mx = -1e30f;
                #pragma unroll
                for (int mt = 0; mt < 4; ++mt)
                    #pragma unroll
                    for (int r = 0; r < 4; ++r) {
                        float v = s[ns][mt][r];
                        int kv = kv0 + mt * 16 + 4 * g4 + r;
                        v = (kv <= qg) ? v : -1e30f;
                        x[mt * 4 + r] = v;
                        mx = fmaxf(mx, v);
                    }
                mx = fmaxf(mx, __shfl_xor(mx, 16));
                mx = fmaxf(mx, __shfl_xor(mx, 32));
                float mn = ms[b][ns];
                if (!__all(mx - mn <= 8.0f)) {        // rescale path
                    mn = fmaxf(mn, mx);
                    float al = __expf(ms[b][ns] - mn);
                    ls[b][ns] *= al;
                    #pragma unroll
                    for (int mt = 0; mt < 4; ++mt) o[b][ns][mt] *= al;
                    ms[b][ns] = mn;
                }
                float rs = 0.f;
                unsigned int pw[8];
                #pragma unroll
                for (int mt = 0; mt < 4; ++mt)
                    #pragma unroll
                    for (int rp = 0; rp < 2; ++rp) {
                        float p0 = __expf(x[mt * 4 + rp * 2]     - mn);
                        float p1 = __expf(x[mt * 4 + rp * 2 + 1] - mn);
                        rs += p0 + p1;
                        pw[mt * 2 + rp] = (unsigned int)f2bf(p0) | ((unsigned int)f2bf(p1) << 16);
                    }
                rs += __shfl_xor(rs, 16);
                rs += __shfl_xor(rs, 32);
                ls[b][ns] += rs;
                unsigned int* prow = (unsigned int*)&PsW[(ns * 16 + l16) * LDP2];
                #pragma unroll
                for (int mt = 0; mt < 4; ++mt)
                    #pragma unroll
                    for (int rp = 0; rp < 2; ++rp)
                        prow[mt * 8 + g4 * 2 + rp] = pw[mt * 2 + rp];
            }

            // ---- O^T += V^T · P^T ----
            #pragma unroll
            for (int kc = 0; kc < 2; ++kc) {
                bf8_t pb[2];
                #pragma unroll
                for (int ns = 0; ns < 2; ++ns)
                    pb[ns] = *(const bf8_t*)&PsW[(ns * 16 + l16) * LDP2 + kc * 32 + 8 * g4];
                #pragma unroll
                for (int mt = 0; mt < 4; ++mt) {
                    bf8_t vf = *(const bf8_t*)&Vb_[(size_t)(mt * 16 + l16) * SEQ
                                                   + kv0 + kc * 32 + 8 * g4];
                    #pragma unroll
                    for (int ns = 0; ns < 2; ++ns)
                        o[b][ns][mt] = __builtin_amdgcn_mfma_f32_16x16x32_bf16(
                            vf, pb[ns], o[b][ns][mt], 0, 0, 0);
                }
            }
        }
    }

    // ---- write partials ----
    #pragma unroll
    for (int b = 0; b < 2; ++b)
        #pragma unroll
        for (int ns = 0; ns < 2; ++ns) {
            int qg = qb[b] + ns * 16 + l16;
            if (g4 == 0) {
                float2 mlv; mlv.x = ms[b][ns]; mlv.y = ls[b][ns];
                *(float2*)&mlpart[((size_t)(ck * NH + h) * SEQ + qg) * 2] = mlv;
            }
            #pragma unroll
            for (int mt = 0; mt < 4; ++mt)
                #pragma unroll
                for (int r = 0; r < 4; ++r)
                    Opart[((size_t)(ck * NH + h) * HD + mt * 16 + 4 * g4 + r) * SEQ + qg]
                        = f2bf(o[b][ns][mt][r]);
        }
}

// ---------------------------------------------------------------------------
// K2b: combine NCK chunks + transpose -> attnb[s][h*64+d] bf16
// ---------------------------------------------------------------------------
__global__ __launch_bounds__(256) void attn_combine_kernel(
    const unsigned short* __restrict__ Opart, const float* __restrict__ mlpart,
    unsigned short* __restrict__ attnb)
{
    __shared__ float comb[64][66];
    __shared__ float wbuf[NCK + 1][64];
    int s0 = blockIdx.x * 64;
    int h  = blockIdx.y;
    int t = threadIdx.x;
    if (t < 64) {
        int s = s0 + t;
        float m[NCK], l[NCK];
        float M = -1e30f;
        #pragma unroll
        for (int c = 0; c < NCK; ++c) {
            float2 ml = *(const float2*)&mlpart[((size_t)(c * NH + h) * SEQ + s) * 2];
            m[c] = ml.x; l[c] = ml.y;
            M = fmaxf(M, m[c]);
        }
        float denom = 0.f;
        #pragma unroll
        for (int c = 0; c < NCK; ++c) {
            float wv = __expf(m[c] - M);
            wbuf[c][t] = wv;
            denom += wv * l[c];
        }
        wbuf[NCK][t] = 1.0f / denom;
    }
    __syncthreads();
    int d = t >> 2, sc = (t & 3) * 16;
    #pragma unroll
    for (int j8 = 0; j8 < 2; ++j8) {
        bf8_t a[NCK];
        #pragma unroll
        for (int c = 0; c < NCK; ++c)
            a[c] = *(const bf8_t*)&Opart[((size_t)(c * NH + h) * HD + d) * SEQ + s0 + sc + j8 * 8];
        #pragma unroll
        for (int j = 0; j < 8; ++j) {
            int s = sc + j8 * 8 + j;
            float accv = 0.f;
            #pragma unroll
            for (int c = 0; c < NCK; ++c)
                accv += wbuf[c][s] * bf2f((unsigned short)a[c][j]);
            comb[d][s] = accv * wbuf[NCK][s];
        }
    }
    __syncthreads();
    int s = t >> 2, dc = (t & 3) * 16;
    unsigned short ob[16];
    #pragma unroll
    for (int j = 0; j < 16; ++j) ob[j] = f2bf(comb[dc + j][s]);
    *(bf8_t*)&attnb[(size_t)(s0 + s) * QCOLS + h * HD + dc]     = *(bf8_t*)&ob[0];
    *(bf8_t*)&attnb[(size_t)(s0 + s) * QCOLS + h * HD + dc + 8] = *(bf8_t*)&ob[8];
}

// ---------------------------------------------------------------------------
extern "C" void kernel_launch(void* const* d_in, const int* in_sizes, int n_in,
                              void* d_out, int out_size, void* d_ws, size_t ws_size,
                              hipStream_t stream) {
    const float* X  = (const float*)d_in[0];
    const float* Wq = (const float*)d_in[2];
    const float* Wk = (const float*)d_in[3];
    const float* Wv = (const float*)d_in[4];
    const float* Wo = (const float*)d_in[5];
    float* out = (float*)d_out;

    float* ws   = (float*)d_ws;
    float* cosT = ws;                                         // 2048*64 f32
    float* sinT = cosT + SEQ*HD;                              // 2048*64 f32
    unsigned short* Xb  = (unsigned short*)(sinT + SEQ*HD);   // 2048*2048 bf16
    unsigned short* WT  = Xb + (size_t)SEQ*HID;               // 3072*2048 bf16
    unsigned short* WoT = WT + (size_t)3072*HID;              // 2048*2048 bf16
    unsigned short* Qb  = WoT + (size_t)HID*HID;              // 2048*2048
    unsigned short* Kb  = Qb + (size_t)SEQ*QCOLS;             // 2048*512
    unsigned short* Vb  = Kb + (size_t)SEQ*KVCOLS;            // 2048*512
    unsigned short* Vtg = Vb + (size_t)SEQ*KVCOLS;            // 512*2048 (V^T)
    unsigned short* attnb = Vtg + (size_t)KVCOLS*SEQ;         // 2048*2048
    unsigned short* Opart = attnb + (size_t)SEQ*QCOLS;        // NCK*32*64*2048 bf16
    float* mlpart = (float*)(Opart + (size_t)NCK*NH*HD*SEQ);  // NCK*32*2048*2 f32

    rope_table_kernel<<<SEQ*HD/256, 256, 0, stream>>>(cosT, sinT);
    convert_x_kernel<<<SEQ*HID/4/256, 256, 0, stream>>>(X, Xb);
    transpose_all_kernel<<<dim3(5120/32, HID/32), 256, 0, stream>>>(Wq, Wk, Wv, Wo, WT, WoT);

    dim3 g1(3072/128, SEQ/128);
    qkv_mfma_kernel<<<g1, 256, 0, stream>>>(Xb, WT, cosT, sinT, Qb, Kb, Vb);
    transpose_v_kernel<<<dim3(SEQ/64, NKV), 256, 0, stream>>>(Vb, Vtg);

    dim3 g2(8, NH, NCK);
    attn_mfma_kernel<<<g2, 256, 0, stream>>>(Qb, Kb, Vtg, Opart, mlpart);
    attn_combine_kernel<<<dim3(SEQ/64, NH), 256, 0, stream>>>(Opart, mlpart, attnb);

    dim3 g3(HID/128, SEQ/128);
    out_mfma_kernel<<<g3, 256, 0, stream>>>(attnb, WoT, out);
}